// Round 6
// baseline (185.283 us; speedup 1.0000x reference)
//
#include <hip/hip_runtime.h>

#define NE 8192
#define DD 256
#define NSPLIT 32

typedef __attribute__((ext_vector_type(8))) short short8;
typedef __attribute__((ext_vector_type(4))) short short4v;
typedef __attribute__((ext_vector_type(8))) __bf16 bf16x8;
typedef __attribute__((ext_vector_type(4))) float floatx4;

__device__ __forceinline__ unsigned short f2bf(float f) {
  union { float f; unsigned int i; } v; v.f = f;
  unsigned int r = v.i + 0x7fffu + ((v.i >> 16) & 1u);
  return (unsigned short)(r >> 16);
}

__device__ __forceinline__ floatx4 mfma_bf16(short8 a, short8 b, floatx4 c) {
  return __builtin_amdgcn_mfma_f32_16x16x32_bf16(
      __builtin_bit_cast(bf16x8, a), __builtin_bit_cast(bf16x8, b), c, 0, 0, 0);
}

// ---------------------------------------------------------------------------
// K1: e_z = relu(x @ W_z + b_z). Tile 128r x 64c, BK=128 (2 rounds).
// grid (4,64,2) = 512 blocks -> 2 blocks/CU. LDS 52,224 B.
// A: x fp32 vector-load + cvt. B: W fp32 4x4-block transpose, staggered b64.
// Designated blocks also emit xT (bf16 [k][row]) from the staged A slab.
__global__ __launch_bounds__(256, 2)
void e_gemm(const float* __restrict__ x,
            const float* __restrict__ W1, const float* __restrict__ b1,
            const float* __restrict__ W2, const float* __restrict__ b2,
            unsigned short* __restrict__ e1, unsigned short* __restrict__ e2,
            unsigned short* __restrict__ e1T, unsigned short* __restrict__ e2T,
            unsigned short* __restrict__ xT)
{
  __shared__ __align__(16) unsigned short smA[128 * 136];  // [row][k]
  __shared__ __align__(16) unsigned short smB[64 * 136];   // [n][k]
  const int T = threadIdx.x, lane = T & 63, wv = T >> 6;
  const int q = lane >> 4, r = lane & 15;
  const int z = blockIdx.z;
  const int col0 = blockIdx.x * 64, row0 = blockIdx.y * 128;
  const float* W = z ? W2 : W1;
  const float* bi = z ? b2 : b1;
  unsigned short* eo = z ? e2 : e1;
  unsigned short* eoT = z ? e2T : e1T;
  const bool emit = (z == 0) && ((int)blockIdx.x == (int)(blockIdx.y & 3));
  const int wr = (wv >> 1) * 64, wc = (wv & 1) * 32;

  floatx4 acc[4][2];
#pragma unroll
  for (int i = 0; i < 4; ++i)
#pragma unroll
    for (int j = 0; j < 2; ++j) acc[i][j] = (floatx4){0.f, 0.f, 0.f, 0.f};

  for (int kc = 0; kc < 256; kc += 128) {
    // A: 128 rows x 128 k fp32 -> bf16
#pragma unroll
    for (int p = 0; p < 16; ++p) {
      const int id = p * 256 + T, rr = id >> 5, k4 = (id & 31) * 4;
      floatx4 v = *(const floatx4*)&x[(size_t)(row0 + rr) * DD + kc + k4];
      short4v s;
#pragma unroll
      for (int c = 0; c < 4; ++c) s[c] = (short)f2bf(v[c]);
      *(short4v*)&smA[rr * 136 + k4] = s;
    }
    // B: transpose W[k][n] -> smB[n][k], 4x4 fp32 blocks, staggered b64 writes
#pragma unroll
    for (int p = 0; p < 2; ++p) {
      const int id = p * 256 + T, kb = id >> 4, n4 = id & 15;
      floatx4 wrow[4];
#pragma unroll
      for (int i = 0; i < 4; ++i)
        wrow[i] = *(const floatx4*)&W[(size_t)(kc + kb * 4 + i) * DD + col0 + n4 * 4];
#pragma unroll
      for (int s4 = 0; s4 < 4; ++s4) {
        const int c = (s4 + n4) & 3;
        short4v sv = {(short)f2bf(wrow[0][c]), (short)f2bf(wrow[1][c]),
                      (short)f2bf(wrow[2][c]), (short)f2bf(wrow[3][c])};
        *(short4v*)&smB[(n4 * 4 + c) * 136 + kb * 4] = sv;
      }
    }
    __syncthreads();
#pragma unroll
    for (int ks = 0; ks < 4; ++ks) {
      short8 af[4], bf[2];
#pragma unroll
      for (int i = 0; i < 4; ++i)
        af[i] = *(const short8*)&smA[(wr + i * 16 + r) * 136 + ks * 32 + q * 8];
#pragma unroll
      for (int j = 0; j < 2; ++j)
        bf[j] = *(const short8*)&smB[(wc + j * 16 + r) * 136 + ks * 32 + q * 8];
#pragma unroll
      for (int i = 0; i < 4; ++i)
#pragma unroll
        for (int j = 0; j < 2; ++j)
          acc[i][j] = mfma_bf16(af[i], bf[j], acc[i][j]);
    }
    if (emit) {
#pragma unroll
      for (int p = 0; p < 8; ++p) {
        const int id = p * 256 + T, kk = id >> 4, r8 = id & 15;
        short8 v;
#pragma unroll
        for (int i = 0; i < 8; ++i) v[i] = (short)smA[(r8 * 8 + i) * 136 + kk];
        *(short8*)&xT[(size_t)(kc + kk) * NE + row0 + r8 * 8] = v;
      }
    }
    __syncthreads();
  }

#pragma unroll
  for (int j = 0; j < 2; ++j) {
    const int col = col0 + wc + j * 16 + r;
    const float bv = bi[col];
#pragma unroll
    for (int i = 0; i < 4; ++i) {
      const int rowb = row0 + wr + i * 16 + q * 4;
      short4v tv;
#pragma unroll
      for (int t = 0; t < 4; ++t) {
        unsigned short h = f2bf(fmaxf(acc[i][j][t] + bv, 0.0f));
        tv[t] = (short)h;
        eo[(size_t)(rowb + t) * DD + col] = h;
      }
      *(short4v*)&eoT[(size_t)col * NE + rowb] = tv;
    }
  }
}

// ---------------------------------------------------------------------------
// K2: split-K partials P[(z*32+y)][fx][fe] (fp32) of G = e_z^T @ x.
// Tile 128(fe) x 64(fx), j-span 256 (2 rounds of 128). grid (8,32,2)=512.
__global__ __launch_bounds__(256, 2)
void atb(const unsigned short* __restrict__ e1T, const unsigned short* __restrict__ e2T,
         const unsigned short* __restrict__ xT, float* __restrict__ P_T)
{
  __shared__ __align__(16) unsigned short smA[128 * 136];  // [fe][j]
  __shared__ __align__(16) unsigned short smB[64 * 136];   // [fx][j]
  const int T = threadIdx.x, lane = T & 63, wv = T >> 6;
  const int q = lane >> 4, r = lane & 15;
  const int m0 = (blockIdx.x >> 2) * 128, n0 = (blockIdx.x & 3) * 64;
  const int y = blockIdx.y, z = blockIdx.z;
  const int j0 = y * 256;
  const unsigned short* E = z ? e2T : e1T;
  float* P = P_T + (size_t)(z * NSPLIT + y) * 65536;
  const int wr = (wv >> 1) * 64, wc = (wv & 1) * 32;

  floatx4 acc[4][2];
#pragma unroll
  for (int i = 0; i < 4; ++i)
#pragma unroll
    for (int j = 0; j < 2; ++j) acc[i][j] = (floatx4){0.f, 0.f, 0.f, 0.f};

  for (int jc = 0; jc < 256; jc += 128) {
#pragma unroll
    for (int p = 0; p < 8; ++p) {
      const int id = p * 256 + T, mm = id >> 4, j8 = (id & 15) * 8;
      *(short8*)&smA[mm * 136 + j8] =
          *(const short8*)&E[(size_t)(m0 + mm) * NE + j0 + jc + j8];
    }
#pragma unroll
    for (int p = 0; p < 4; ++p) {
      const int id = p * 256 + T, nn = id >> 4, j8 = (id & 15) * 8;
      *(short8*)&smB[nn * 136 + j8] =
          *(const short8*)&xT[(size_t)(n0 + nn) * NE + j0 + jc + j8];
    }
    __syncthreads();
#pragma unroll
    for (int ks = 0; ks < 4; ++ks) {
      short8 af[4], bf[2];
#pragma unroll
      for (int i = 0; i < 4; ++i)
        af[i] = *(const short8*)&smA[(wr + i * 16 + r) * 136 + ks * 32 + q * 8];
#pragma unroll
      for (int j = 0; j < 2; ++j)
        bf[j] = *(const short8*)&smB[(wc + j * 16 + r) * 136 + ks * 32 + q * 8];
#pragma unroll
      for (int i = 0; i < 4; ++i)
#pragma unroll
        for (int j = 0; j < 2; ++j)
          acc[i][j] = mfma_bf16(af[i], bf[j], acc[i][j]);
    }
    __syncthreads();
  }
#pragma unroll
  for (int i = 0; i < 4; ++i)
#pragma unroll
    for (int j = 0; j < 2; ++j) {
      const int n = n0 + wc + j * 16 + r;
      const int m = m0 + wr + i * 16 + q * 4;
      *(floatx4*)&P[(size_t)n * DD + m] = acc[i][j];
    }
}

// ---------------------------------------------------------------------------
// K3: H_z^T = ((sum_y P)/256 @ W3seg)^T, inline 32-way reduce (P read once).
// grid 32: z (2) x fe-tile (16 of width 16). l processed in 4 chunks of 64.
__global__ __launch_bounds__(256, 1)
void h_mfma(const float* __restrict__ P_T, const float* __restrict__ W3,
            unsigned short* __restrict__ H1t, unsigned short* __restrict__ H2t)
{
  __shared__ __align__(16) unsigned short smA[16 * 72];    // [fe][l-chunk]
  __shared__ __align__(16) unsigned short smB[256 * 72];   // [m][l-chunk]
  const int T = threadIdx.x, lane = T & 63, wv = T >> 6;
  const int q = lane >> 4, r = lane & 15;
  const int z = blockIdx.x >> 4, ft = blockIdx.x & 15;
  const int k0 = ft * 16;
  const float* P = P_T + (size_t)z * NSPLIT * 65536;
  unsigned short* Ht = z ? H2t : H1t;
  const int woff = 256 + z * 256;
  const int wc = wv * 64;

  floatx4 acc[4];
#pragma unroll
  for (int j = 0; j < 4; ++j) acc[j] = (floatx4){0.f, 0.f, 0.f, 0.f};

  for (int lc = 0; lc < 256; lc += 64) {
    {  // A: G[fe][l] = sum_y P[y][l][fe], transposed store
      const int l = T >> 2, fe4 = T & 3;
      floatx4 g = (floatx4){0.f, 0.f, 0.f, 0.f};
#pragma unroll
      for (int y = 0; y < NSPLIT; ++y)
        g += *(const floatx4*)&P[(size_t)y * 65536 + (size_t)(lc + l) * DD + k0 + fe4 * 4];
#pragma unroll
      for (int i = 0; i < 4; ++i)
        smA[(fe4 * 4 + i) * 72 + l] = f2bf(g[i]);
    }
    // B: transpose W3seg[l][m] -> smB[m][l], staggered b64
#pragma unroll
    for (int p = 0; p < 4; ++p) {
      const int id = p * 256 + T, lb = id >> 6, m4 = id & 63;
      floatx4 wrow[4];
#pragma unroll
      for (int i = 0; i < 4; ++i)
        wrow[i] = *(const floatx4*)&W3[(size_t)(woff + lc + lb * 4 + i) * DD + m4 * 4];
#pragma unroll
      for (int s4 = 0; s4 < 4; ++s4) {
        const int c = (s4 + m4) & 3;
        short4v sv = {(short)f2bf(wrow[0][c]), (short)f2bf(wrow[1][c]),
                      (short)f2bf(wrow[2][c]), (short)f2bf(wrow[3][c])};
        *(short4v*)&smB[(m4 * 4 + c) * 72 + lb * 4] = sv;
      }
    }
    __syncthreads();
#pragma unroll
    for (int ks = 0; ks < 2; ++ks) {
      short8 af = *(const short8*)&smA[r * 72 + ks * 32 + q * 8];
#pragma unroll
      for (int j = 0; j < 4; ++j) {
        short8 bf = *(const short8*)&smB[(wc + j * 16 + r) * 72 + ks * 32 + q * 8];
        acc[j] = mfma_bf16(af, bf, acc[j]);
      }
    }
    __syncthreads();
  }
#pragma unroll
  for (int j = 0; j < 4; ++j) {
    const int m = wc + j * 16 + r;
    short4v v;
#pragma unroll
    for (int i = 0; i < 4; ++i) v[i] = (short)f2bf(acc[j][i] * 0.00390625f);
    *(short4v*)&Ht[(size_t)m * DD + k0 + q * 4] = v;
  }
}

// ---------------------------------------------------------------------------
// K4: out = relu(x@W3a + e1@H1 + e2@H2 + b3), fp32. Tile 64x64, BK=128,
// 3 segs x 2 rounds. grid (4,128)=512 -> 2 blocks/CU. LDS 34,816 B.
__global__ __launch_bounds__(256, 2)
void out_gemm(const float* __restrict__ x,
              const unsigned short* __restrict__ e1, const unsigned short* __restrict__ e2,
              const float* __restrict__ W3,
              const unsigned short* __restrict__ H1t, const unsigned short* __restrict__ H2t,
              const float* __restrict__ b3, float* __restrict__ out)
{
  __shared__ __align__(16) unsigned short smA[64 * 136];  // [row][k]
  __shared__ __align__(16) unsigned short smB[64 * 136];  // [col][k]
  const int T = threadIdx.x, lane = T & 63, wv = T >> 6;
  const int q = lane >> 4, r = lane & 15;
  const int col0 = blockIdx.x * 64, row0 = blockIdx.y * 64;

  floatx4 acc[4];
#pragma unroll
  for (int j = 0; j < 4; ++j) acc[j] = (floatx4){0.f, 0.f, 0.f, 0.f};

  for (int s = 0; s < 3; ++s) {
    for (int kc = 0; kc < 256; kc += 128) {
      if (s == 0) {
#pragma unroll
        for (int p = 0; p < 8; ++p) {
          const int id = p * 256 + T, rr = id >> 5, k4 = (id & 31) * 4;
          floatx4 v = *(const floatx4*)&x[(size_t)(row0 + rr) * DD + kc + k4];
          short4v sv;
#pragma unroll
          for (int c = 0; c < 4; ++c) sv[c] = (short)f2bf(v[c]);
          *(short4v*)&smA[rr * 136 + k4] = sv;
        }
#pragma unroll
        for (int p = 0; p < 2; ++p) {
          const int id = p * 256 + T, kb = id >> 4, n4 = id & 15;
          floatx4 wrow[4];
#pragma unroll
          for (int i = 0; i < 4; ++i)
            wrow[i] = *(const floatx4*)&W3[(size_t)(kc + kb * 4 + i) * DD + col0 + n4 * 4];
#pragma unroll
          for (int s4 = 0; s4 < 4; ++s4) {
            const int c = (s4 + n4) & 3;
            short4v sv = {(short)f2bf(wrow[0][c]), (short)f2bf(wrow[1][c]),
                          (short)f2bf(wrow[2][c]), (short)f2bf(wrow[3][c])};
            *(short4v*)&smB[(n4 * 4 + c) * 136 + kb * 4] = sv;
          }
        }
      } else {
        const unsigned short* E = (s == 1) ? e1 : e2;
        const unsigned short* Hs = (s == 1) ? H1t : H2t;
#pragma unroll
        for (int p = 0; p < 4; ++p) {
          const int id = p * 256 + T, rr = id >> 4, j8 = (id & 15) * 8;
          *(short8*)&smA[rr * 136 + j8] =
              *(const short8*)&E[(size_t)(row0 + rr) * DD + kc + j8];
          *(short8*)&smB[rr * 136 + j8] =
              *(const short8*)&Hs[(size_t)(col0 + rr) * DD + kc + j8];
        }
      }
      __syncthreads();
#pragma unroll
      for (int ks = 0; ks < 4; ++ks) {
        short8 af = *(const short8*)&smA[(wv * 16 + r) * 136 + ks * 32 + q * 8];
#pragma unroll
        for (int j = 0; j < 4; ++j) {
          short8 bf = *(const short8*)&smB[(j * 16 + r) * 136 + ks * 32 + q * 8];
          acc[j] = mfma_bf16(af, bf, acc[j]);
        }
      }
      __syncthreads();
    }
  }
#pragma unroll
  for (int j = 0; j < 4; ++j) {
    const int col = col0 + j * 16 + r;
    const float bv = b3[col];
    const int rowb = row0 + wv * 16 + q * 4;
#pragma unroll
    for (int t = 0; t < 4; ++t)
      out[(size_t)(rowb + t) * DD + col] = fmaxf(acc[j][t] + bv, 0.0f);
  }
}

// ---------------------------------------------------------------------------
extern "C" void kernel_launch(void* const* d_in, const int* in_sizes, int n_in,
                              void* d_out, int out_size, void* d_ws, size_t ws_size,
                              hipStream_t stream) {
  (void)in_sizes; (void)n_in; (void)out_size; (void)ws_size;
  const float* x  = (const float*)d_in[3];
  const float* W1 = (const float*)d_in[5];
  const float* b1 = (const float*)d_in[6];
  const float* W2 = (const float*)d_in[7];
  const float* b2 = (const float*)d_in[8];
  const float* W3 = (const float*)d_in[9];
  const float* b3 = (const float*)d_in[10];
  float* out = (float*)d_out;

  char* ws = (char*)d_ws;
  const size_t MB = 1u << 20;
  const size_t KB = 1u << 10;
  unsigned short* e1  = (unsigned short*)ws;                          // 4 MB
  unsigned short* e2  = (unsigned short*)(ws + 4 * MB);               // 4 MB
  unsigned short* e1T = (unsigned short*)(ws + 8 * MB);               // 4 MB
  unsigned short* e2T = (unsigned short*)(ws + 12 * MB);              // 4 MB
  unsigned short* xT  = (unsigned short*)(ws + 16 * MB);              // 4 MB
  unsigned short* H1t = (unsigned short*)(ws + 20 * MB);              // 128 KB
  unsigned short* H2t = (unsigned short*)(ws + 20 * MB + 128 * KB);   // 128 KB
  float* P_T          = (float*)(ws + 21 * MB);                       // 16 MB

  e_gemm<<<dim3(4, 64, 2), 256, 0, stream>>>(x, W1, b1, W2, b2, e1, e2, e1T, e2T, xT);
  atb<<<dim3(8, NSPLIT, 2), 256, 0, stream>>>(e1T, e2T, xT, P_T);
  h_mfma<<<32, 256, 0, stream>>>(P_T, W3, H1t, H2t);
  out_gemm<<<dim3(4, 128), 256, 0, stream>>>(x, e1, e2, W3, H1t, H2t, b3, out);
}

// Round 7
// 137.116 us; speedup vs baseline: 1.3513x; 1.3513x over previous
//
#include <hip/hip_runtime.h>

#define NE 8192
#define DD 256
#define NSPLIT 16

typedef __attribute__((ext_vector_type(8))) short short8;
typedef __attribute__((ext_vector_type(4))) short short4v;
typedef __attribute__((ext_vector_type(8))) __bf16 bf16x8;
typedef __attribute__((ext_vector_type(4))) float floatx4;

__device__ __forceinline__ unsigned short f2bf(float f) {
  union { float f; unsigned int i; } v; v.f = f;
  unsigned int r = v.i + 0x7fffu + ((v.i >> 16) & 1u);
  return (unsigned short)(r >> 16);
}

__device__ __forceinline__ floatx4 mfma_bf16(short8 a, short8 b, floatx4 c) {
  return __builtin_amdgcn_mfma_f32_16x16x32_bf16(
      __builtin_bit_cast(bf16x8, a), __builtin_bit_cast(bf16x8, b), c, 0, 0, 0);
}

// ---------------------------------------------------------------------------
// K1: e_z = relu(x @ W_z + b_z). Tile 128r x 64c, BK=128 (2 rounds).
// grid (4,64,2) = 512 blocks -> 2 blocks/CU. LDS 52,224 B.
__global__ __launch_bounds__(256, 2)
void e_gemm(const float* __restrict__ x,
            const float* __restrict__ W1, const float* __restrict__ b1,
            const float* __restrict__ W2, const float* __restrict__ b2,
            unsigned short* __restrict__ e1, unsigned short* __restrict__ e2,
            unsigned short* __restrict__ e1T, unsigned short* __restrict__ e2T,
            unsigned short* __restrict__ xT)
{
  __shared__ __align__(16) unsigned short smA[128 * 136];  // [row][k]
  __shared__ __align__(16) unsigned short smB[64 * 136];   // [n][k]
  const int T = threadIdx.x, lane = T & 63, wv = T >> 6;
  const int q = lane >> 4, r = lane & 15;
  const int z = blockIdx.z;
  const int col0 = blockIdx.x * 64, row0 = blockIdx.y * 128;
  const float* W = z ? W2 : W1;
  const float* bi = z ? b2 : b1;
  unsigned short* eo = z ? e2 : e1;
  unsigned short* eoT = z ? e2T : e1T;
  const bool emit = (z == 0) && ((int)blockIdx.x == (int)(blockIdx.y & 3));
  const int wr = (wv >> 1) * 64, wc = (wv & 1) * 32;

  floatx4 acc[4][2];
#pragma unroll
  for (int i = 0; i < 4; ++i)
#pragma unroll
    for (int j = 0; j < 2; ++j) acc[i][j] = (floatx4){0.f, 0.f, 0.f, 0.f};

  for (int kc = 0; kc < 256; kc += 128) {
#pragma unroll
    for (int p = 0; p < 16; ++p) {
      const int id = p * 256 + T, rr = id >> 5, k4 = (id & 31) * 4;
      floatx4 v = *(const floatx4*)&x[(size_t)(row0 + rr) * DD + kc + k4];
      short4v s;
#pragma unroll
      for (int c = 0; c < 4; ++c) s[c] = (short)f2bf(v[c]);
      *(short4v*)&smA[rr * 136 + k4] = s;
    }
#pragma unroll
    for (int p = 0; p < 2; ++p) {
      const int id = p * 256 + T, kb = id >> 4, n4 = id & 15;
      floatx4 wrow[4];
#pragma unroll
      for (int i = 0; i < 4; ++i)
        wrow[i] = *(const floatx4*)&W[(size_t)(kc + kb * 4 + i) * DD + col0 + n4 * 4];
#pragma unroll
      for (int s4 = 0; s4 < 4; ++s4) {
        const int c = (s4 + n4) & 3;
        short4v sv = {(short)f2bf(wrow[0][c]), (short)f2bf(wrow[1][c]),
                      (short)f2bf(wrow[2][c]), (short)f2bf(wrow[3][c])};
        *(short4v*)&smB[(n4 * 4 + c) * 136 + kb * 4] = sv;
      }
    }
    __syncthreads();
#pragma unroll
    for (int ks = 0; ks < 4; ++ks) {
      short8 af[4], bf[2];
#pragma unroll
      for (int i = 0; i < 4; ++i)
        af[i] = *(const short8*)&smA[(wr + i * 16 + r) * 136 + ks * 32 + q * 8];
#pragma unroll
      for (int j = 0; j < 2; ++j)
        bf[j] = *(const short8*)&smB[(wc + j * 16 + r) * 136 + ks * 32 + q * 8];
#pragma unroll
      for (int i = 0; i < 4; ++i)
#pragma unroll
        for (int j = 0; j < 2; ++j)
          acc[i][j] = mfma_bf16(af[i], bf[j], acc[i][j]);
    }
    if (emit) {
#pragma unroll
      for (int p = 0; p < 8; ++p) {
        const int id = p * 256 + T, kk = id >> 4, r8 = id & 15;
        short8 v;
#pragma unroll
        for (int i = 0; i < 8; ++i) v[i] = (short)smA[(r8 * 8 + i) * 136 + kk];
        *(short8*)&xT[(size_t)(kc + kk) * NE + row0 + r8 * 8] = v;
      }
    }
    __syncthreads();
  }

#pragma unroll
  for (int j = 0; j < 2; ++j) {
    const int col = col0 + wc + j * 16 + r;
    const float bv = bi[col];
#pragma unroll
    for (int i = 0; i < 4; ++i) {
      const int rowb = row0 + wr + i * 16 + q * 4;
      short4v tv;
#pragma unroll
      for (int t = 0; t < 4; ++t) {
        unsigned short h = f2bf(fmaxf(acc[i][j][t] + bv, 0.0f));
        tv[t] = (short)h;
        eo[(size_t)(rowb + t) * DD + col] = h;
      }
      *(short4v*)&eoT[(size_t)col * NE + rowb] = tv;
    }
  }
}

// ---------------------------------------------------------------------------
// K2: split-K partials P[(z*16+y)][n][m] of G = e_z^T @ x.
// Tile 64(m=fe) x 64(n=fx), j-span 512 (4 rounds of 128). grid (16,16,2)=512.
__global__ __launch_bounds__(256, 2)
void atb(const unsigned short* __restrict__ e1T, const unsigned short* __restrict__ e2T,
         const unsigned short* __restrict__ xT, float* __restrict__ P_T)
{
  __shared__ __align__(16) unsigned short smA[64 * 136];  // [m][j]
  __shared__ __align__(16) unsigned short smB[64 * 136];  // [n][j]
  const int T = threadIdx.x, lane = T & 63, wv = T >> 6;
  const int q = lane >> 4, r = lane & 15;
  const int m0 = (blockIdx.x >> 2) * 64, n0 = (blockIdx.x & 3) * 64;
  const int y = blockIdx.y, z = blockIdx.z;
  const int j0 = y * (NE / NSPLIT);
  const unsigned short* E = z ? e2T : e1T;
  float* P = P_T + (size_t)(z * NSPLIT + y) * 65536;

  floatx4 acc[4];
#pragma unroll
  for (int j = 0; j < 4; ++j) acc[j] = (floatx4){0.f, 0.f, 0.f, 0.f};

  for (int jc = 0; jc < NE / NSPLIT; jc += 128) {
#pragma unroll
    for (int p = 0; p < 4; ++p) {
      const int id = p * 256 + T, mm = id >> 4, j8 = (id & 15) * 8;
      *(short8*)&smA[mm * 136 + j8] =
          *(const short8*)&E[(size_t)(m0 + mm) * NE + j0 + jc + j8];
      *(short8*)&smB[mm * 136 + j8] =
          *(const short8*)&xT[(size_t)(n0 + mm) * NE + j0 + jc + j8];
    }
    __syncthreads();
#pragma unroll
    for (int ks = 0; ks < 4; ++ks) {
      short8 af = *(const short8*)&smA[(wv * 16 + r) * 136 + ks * 32 + q * 8];
#pragma unroll
      for (int j = 0; j < 4; ++j) {
        short8 bf = *(const short8*)&smB[(j * 16 + r) * 136 + ks * 32 + q * 8];
        acc[j] = mfma_bf16(af, bf, acc[j]);
      }
    }
    __syncthreads();
  }
#pragma unroll
  for (int j = 0; j < 4; ++j) {
    const int n = n0 + j * 16 + r;
    const int m = m0 + wv * 16 + q * 4;
    *(floatx4*)&P[(size_t)n * DD + m] = acc[j];
  }
}

// ---------------------------------------------------------------------------
// K3: G_T[z][n][m] = sum_y P. 8 MB coalesced read, 128 blocks x 256 thr.
__global__ void reduce_g(const float* __restrict__ P_T, float* __restrict__ G_T) {
  int idx = blockIdx.x * 256 + threadIdx.x;        // 0..32767 floatx4
  int z = idx >> 14, off = idx & 16383;
  const floatx4* Pp = (const floatx4*)P_T;
  floatx4 s = (floatx4){0.f, 0.f, 0.f, 0.f};
#pragma unroll
  for (int y = 0; y < NSPLIT; ++y)
    s += Pp[(size_t)(z * NSPLIT + y) * 16384 + off];
  ((floatx4*)G_T)[idx] = s;
}

// ---------------------------------------------------------------------------
// K4: Ht_z[m3][me] = H_z^T, H_z = (G_z/256) @ W3seg_z. Tiles 64(me)x64(m3),
// grid (16,1,2)=32 blocks on 512 KB G_T + 1 MB W3 (L2-hot). BK=128.
// A[M=me][K=l] = transpose of G_T (scaled); B[N=m3][K=l] = W3seg^T.
__global__ __launch_bounds__(256, 2)
void h_mfma(const float* __restrict__ G_T, const float* __restrict__ W3,
            unsigned short* __restrict__ H1t, unsigned short* __restrict__ H2t)
{
  __shared__ __align__(16) unsigned short smA[64 * 136];
  __shared__ __align__(16) unsigned short smB[64 * 136];
  const int T = threadIdx.x, lane = T & 63, wv = T >> 6;
  const int q = lane >> 4, r = lane & 15;
  const int z = blockIdx.z;
  const int me0 = (blockIdx.x >> 2) * 64, m30 = (blockIdx.x & 3) * 64;
  const float* G = G_T + (size_t)z * 65536;
  unsigned short* Ht = z ? H2t : H1t;
  const int woff = 256 + z * 256;

  floatx4 acc[4];
#pragma unroll
  for (int j = 0; j < 4; ++j) acc[j] = (floatx4){0.f, 0.f, 0.f, 0.f};

  for (int lc = 0; lc < 256; lc += 128) {
#pragma unroll
    for (int p = 0; p < 2; ++p) {
      const int id = p * 256 + T, lb = id >> 4, e4 = id & 15;
      floatx4 grow[4], wrow[4];
#pragma unroll
      for (int i = 0; i < 4; ++i) {
        grow[i] = *(const floatx4*)&G[(size_t)(lc + lb * 4 + i) * DD + me0 + e4 * 4];
        wrow[i] = *(const floatx4*)&W3[(size_t)(woff + lc + lb * 4 + i) * DD + m30 + e4 * 4];
      }
#pragma unroll
      for (int s4 = 0; s4 < 4; ++s4) {
        const int c = (s4 + e4) & 3;
        short4v ga = {(short)f2bf(grow[0][c] * 0.00390625f),
                      (short)f2bf(grow[1][c] * 0.00390625f),
                      (short)f2bf(grow[2][c] * 0.00390625f),
                      (short)f2bf(grow[3][c] * 0.00390625f)};
        short4v wa = {(short)f2bf(wrow[0][c]), (short)f2bf(wrow[1][c]),
                      (short)f2bf(wrow[2][c]), (short)f2bf(wrow[3][c])};
        *(short4v*)&smA[(e4 * 4 + c) * 136 + lb * 4] = ga;
        *(short4v*)&smB[(e4 * 4 + c) * 136 + lb * 4] = wa;
      }
    }
    __syncthreads();
#pragma unroll
    for (int ks = 0; ks < 4; ++ks) {
      short8 af = *(const short8*)&smA[(wv * 16 + r) * 136 + ks * 32 + q * 8];
#pragma unroll
      for (int j = 0; j < 4; ++j) {
        short8 bf = *(const short8*)&smB[(j * 16 + r) * 136 + ks * 32 + q * 8];
        acc[j] = mfma_bf16(af, bf, acc[j]);
      }
    }
    __syncthreads();
  }
#pragma unroll
  for (int j = 0; j < 4; ++j) {
    const int m3 = m30 + j * 16 + r;
    const int me = me0 + wv * 16 + q * 4;
    short4v v;
#pragma unroll
    for (int i = 0; i < 4; ++i) v[i] = (short)f2bf(acc[j][i]);
    *(short4v*)&Ht[(size_t)m3 * DD + me] = v;
  }
}

// ---------------------------------------------------------------------------
// K5: out = relu(x@W3a + e1@H1 + e2@H2 + b3), fp32. Tile 64x64, BK=128,
// 3 segs x 2 rounds. grid (4,128)=512 -> 2 blocks/CU.
__global__ __launch_bounds__(256, 2)
void out_gemm(const float* __restrict__ x,
              const unsigned short* __restrict__ e1, const unsigned short* __restrict__ e2,
              const float* __restrict__ W3,
              const unsigned short* __restrict__ H1t, const unsigned short* __restrict__ H2t,
              const float* __restrict__ b3, float* __restrict__ out)
{
  __shared__ __align__(16) unsigned short smA[64 * 136];
  __shared__ __align__(16) unsigned short smB[64 * 136];
  const int T = threadIdx.x, lane = T & 63, wv = T >> 6;
  const int q = lane >> 4, r = lane & 15;
  const int col0 = blockIdx.x * 64, row0 = blockIdx.y * 64;

  floatx4 acc[4];
#pragma unroll
  for (int j = 0; j < 4; ++j) acc[j] = (floatx4){0.f, 0.f, 0.f, 0.f};

  for (int s = 0; s < 3; ++s) {
    for (int kc = 0; kc < 256; kc += 128) {
      if (s == 0) {
#pragma unroll
        for (int p = 0; p < 8; ++p) {
          const int id = p * 256 + T, rr = id >> 5, k4 = (id & 31) * 4;
          floatx4 v = *(const floatx4*)&x[(size_t)(row0 + rr) * DD + kc + k4];
          short4v sv;
#pragma unroll
          for (int c = 0; c < 4; ++c) sv[c] = (short)f2bf(v[c]);
          *(short4v*)&smA[rr * 136 + k4] = sv;
        }
#pragma unroll
        for (int p = 0; p < 2; ++p) {
          const int id = p * 256 + T, kb = id >> 4, n4 = id & 15;
          floatx4 wrow[4];
#pragma unroll
          for (int i = 0; i < 4; ++i)
            wrow[i] = *(const floatx4*)&W3[(size_t)(kc + kb * 4 + i) * DD + col0 + n4 * 4];
#pragma unroll
          for (int s4 = 0; s4 < 4; ++s4) {
            const int c = (s4 + n4) & 3;
            short4v sv = {(short)f2bf(wrow[0][c]), (short)f2bf(wrow[1][c]),
                          (short)f2bf(wrow[2][c]), (short)f2bf(wrow[3][c])};
            *(short4v*)&smB[(n4 * 4 + c) * 136 + kb * 4] = sv;
          }
        }
      } else {
        const unsigned short* E = (s == 1) ? e1 : e2;
        const unsigned short* Hs = (s == 1) ? H1t : H2t;
#pragma unroll
        for (int p = 0; p < 4; ++p) {
          const int id = p * 256 + T, rr = id >> 4, j8 = (id & 15) * 8;
          *(short8*)&smA[rr * 136 + j8] =
              *(const short8*)&E[(size_t)(row0 + rr) * DD + kc + j8];
          *(short8*)&smB[rr * 136 + j8] =
              *(const short8*)&Hs[(size_t)(col0 + rr) * DD + kc + j8];
        }
      }
      __syncthreads();
#pragma unroll
      for (int ks = 0; ks < 4; ++ks) {
        short8 af = *(const short8*)&smA[(wv * 16 + r) * 136 + ks * 32 + q * 8];
#pragma unroll
        for (int j = 0; j < 4; ++j) {
          short8 bf = *(const short8*)&smB[(j * 16 + r) * 136 + ks * 32 + q * 8];
          acc[j] = mfma_bf16(af, bf, acc[j]);
        }
      }
      __syncthreads();
    }
  }
#pragma unroll
  for (int j = 0; j < 4; ++j) {
    const int col = col0 + j * 16 + r;
    const float bv = b3[col];
    const int rowb = row0 + wv * 16 + q * 4;
#pragma unroll
    for (int t = 0; t < 4; ++t)
      out[(size_t)(rowb + t) * DD + col] = fmaxf(acc[j][t] + bv, 0.0f);
  }
}

// ---------------------------------------------------------------------------
extern "C" void kernel_launch(void* const* d_in, const int* in_sizes, int n_in,
                              void* d_out, int out_size, void* d_ws, size_t ws_size,
                              hipStream_t stream) {
  (void)in_sizes; (void)n_in; (void)out_size; (void)ws_size;
  const float* x  = (const float*)d_in[3];
  const float* W1 = (const float*)d_in[5];
  const float* b1 = (const float*)d_in[6];
  const float* W2 = (const float*)d_in[7];
  const float* b2 = (const float*)d_in[8];
  const float* W3 = (const float*)d_in[9];
  const float* b3 = (const float*)d_in[10];
  float* out = (float*)d_out;

  char* ws = (char*)d_ws;
  const size_t MB = 1u << 20;
  const size_t KB = 1u << 10;
  unsigned short* e1  = (unsigned short*)ws;                          // 4 MB
  unsigned short* e2  = (unsigned short*)(ws + 4 * MB);               // 4 MB
  unsigned short* e1T = (unsigned short*)(ws + 8 * MB);               // 4 MB
  unsigned short* e2T = (unsigned short*)(ws + 12 * MB);              // 4 MB
  unsigned short* xT  = (unsigned short*)(ws + 16 * MB);              // 4 MB
  unsigned short* H1t = (unsigned short*)(ws + 20 * MB);              // 128 KB
  unsigned short* H2t = (unsigned short*)(ws + 20 * MB + 128 * KB);   // 128 KB
  float* G_T          = (float*)(ws + 20 * MB + 256 * KB);            // 512 KB
  float* P_T          = (float*)(ws + 21 * MB);                       // 8 MB

  e_gemm<<<dim3(4, 64, 2), 256, 0, stream>>>(x, W1, b1, W2, b2, e1, e2, e1T, e2T, xT);
  atb<<<dim3(16, NSPLIT, 2), 256, 0, stream>>>(e1T, e2T, xT, P_T);
  reduce_g<<<128, 256, 0, stream>>>(P_T, G_T);
  h_mfma<<<dim3(16, 1, 2), 256, 0, stream>>>(G_T, W3, H1t, H2t);
  out_gemm<<<dim3(4, 128), 256, 0, stream>>>(x, e1, e2, W3, H1t, H2t, b3, out);
}

// Round 8
// 134.743 us; speedup vs baseline: 1.3751x; 1.0176x over previous
//
#include <hip/hip_runtime.h>

#define NE 8192
#define DD 256
#define NSPLIT 32

typedef __attribute__((ext_vector_type(8))) short short8;
typedef __attribute__((ext_vector_type(4))) short short4v;
typedef __attribute__((ext_vector_type(8))) __bf16 bf16x8;
typedef __attribute__((ext_vector_type(4))) float floatx4;

__device__ __forceinline__ unsigned short f2bf(float f) {
  union { float f; unsigned int i; } v; v.f = f;
  unsigned int r = v.i + 0x7fffu + ((v.i >> 16) & 1u);
  return (unsigned short)(r >> 16);
}

__device__ __forceinline__ floatx4 mfma_bf16(short8 a, short8 b, floatx4 c) {
  return __builtin_amdgcn_mfma_f32_16x16x32_bf16(
      __builtin_bit_cast(bf16x8, a), __builtin_bit_cast(bf16x8, b), c, 0, 0, 0);
}

// ---------------------------------------------------------------------------
// K1: e1 AND e2 tiles from one block (x staged once, two W slabs).
// Tile 64r x 64c, BK=128 (2 rounds). grid (4,128)=512, LDS 52,224 B -> 3/CU.
// Designated blocks (x == y&3) also emit xT[k][row] bf16 from the A slab.
__global__ __launch_bounds__(256, 3)
void e_gemm(const float* __restrict__ x,
            const float* __restrict__ W1, const float* __restrict__ b1,
            const float* __restrict__ W2, const float* __restrict__ b2,
            unsigned short* __restrict__ e1, unsigned short* __restrict__ e2,
            unsigned short* __restrict__ e1T, unsigned short* __restrict__ e2T,
            unsigned short* __restrict__ xT)
{
  __shared__ __align__(16) unsigned short smA[64 * 136];   // [row][k]
  __shared__ __align__(16) unsigned short smB1[64 * 136];  // [n][k] W1^T
  __shared__ __align__(16) unsigned short smB2[64 * 136];  // [n][k] W2^T
  const int T = threadIdx.x, lane = T & 63, wv = T >> 6;
  const int q = lane >> 4, r = lane & 15;
  const int col0 = blockIdx.x * 64, row0 = blockIdx.y * 64;
  const bool emit = ((int)blockIdx.x == (int)(blockIdx.y & 3));

  floatx4 acc1[4], acc2[4];
#pragma unroll
  for (int j = 0; j < 4; ++j) {
    acc1[j] = (floatx4){0.f, 0.f, 0.f, 0.f};
    acc2[j] = (floatx4){0.f, 0.f, 0.f, 0.f};
  }

  for (int kc = 0; kc < 256; kc += 128) {
    // A: x[row0..+64][kc..+128] fp32 -> bf16
#pragma unroll
    for (int p = 0; p < 8; ++p) {
      const int id = p * 256 + T, rr = id >> 5, k4 = (id & 31) * 4;
      floatx4 v = *(const floatx4*)&x[(size_t)(row0 + rr) * DD + kc + k4];
      short4v s;
#pragma unroll
      for (int c = 0; c < 4; ++c) s[c] = (short)f2bf(v[c]);
      *(short4v*)&smA[rr * 136 + k4] = s;
    }
    // B: transpose W1,W2 [k][n] -> [n][k], 4x4 fp32 blocks, staggered writes
#pragma unroll
    for (int p = 0; p < 2; ++p) {
      const int id = p * 256 + T, kb = id >> 4, n4 = id & 15;
      floatx4 w1r[4], w2r[4];
#pragma unroll
      for (int i = 0; i < 4; ++i) {
        w1r[i] = *(const floatx4*)&W1[(size_t)(kc + kb * 4 + i) * DD + col0 + n4 * 4];
        w2r[i] = *(const floatx4*)&W2[(size_t)(kc + kb * 4 + i) * DD + col0 + n4 * 4];
      }
#pragma unroll
      for (int s4 = 0; s4 < 4; ++s4) {
        const int c = (s4 + n4) & 3;
        short4v s1 = {(short)f2bf(w1r[0][c]), (short)f2bf(w1r[1][c]),
                      (short)f2bf(w1r[2][c]), (short)f2bf(w1r[3][c])};
        short4v s2 = {(short)f2bf(w2r[0][c]), (short)f2bf(w2r[1][c]),
                      (short)f2bf(w2r[2][c]), (short)f2bf(w2r[3][c])};
        *(short4v*)&smB1[(n4 * 4 + c) * 136 + kb * 4] = s1;
        *(short4v*)&smB2[(n4 * 4 + c) * 136 + kb * 4] = s2;
      }
    }
    __syncthreads();
#pragma unroll
    for (int ks = 0; ks < 4; ++ks) {
      short8 af = *(const short8*)&smA[(wv * 16 + r) * 136 + ks * 32 + q * 8];
#pragma unroll
      for (int j = 0; j < 4; ++j) {
        short8 b1f = *(const short8*)&smB1[(j * 16 + r) * 136 + ks * 32 + q * 8];
        short8 b2f = *(const short8*)&smB2[(j * 16 + r) * 136 + ks * 32 + q * 8];
        acc1[j] = mfma_bf16(af, b1f, acc1[j]);
        acc2[j] = mfma_bf16(af, b2f, acc2[j]);
      }
    }
    if (emit) {   // xT[kc+kk][row0 + r8..+8]
#pragma unroll
      for (int p = 0; p < 4; ++p) {
        const int id = p * 256 + T, kk = id >> 3, r8 = (id & 7) * 8;
        short8 v;
#pragma unroll
        for (int i = 0; i < 8; ++i) v[i] = (short)smA[(r8 + i) * 136 + kk];
        *(short8*)&xT[(size_t)(kc + kk) * NE + row0 + r8] = v;
      }
    }
    __syncthreads();
  }

#pragma unroll
  for (int j = 0; j < 4; ++j) {
    const int col = col0 + j * 16 + r;
    const int rowb = row0 + wv * 16 + q * 4;
    const float b1v = b1[col], b2v = b2[col];
    short4v t1, t2;
#pragma unroll
    for (int t = 0; t < 4; ++t) {
      unsigned short h1 = f2bf(fmaxf(acc1[j][t] + b1v, 0.0f));
      unsigned short h2 = f2bf(fmaxf(acc2[j][t] + b2v, 0.0f));
      t1[t] = (short)h1; t2[t] = (short)h2;
      e1[(size_t)(rowb + t) * DD + col] = h1;
      e2[(size_t)(rowb + t) * DD + col] = h2;
    }
    *(short4v*)&e1T[(size_t)col * NE + rowb] = t1;
    *(short4v*)&e2T[(size_t)col * NE + rowb] = t2;
  }
}

// ---------------------------------------------------------------------------
// K2: split-K partials P[(z*32+y)][n][m] of G = e_z^T @ x.
// Tile 64x64, j-span 256 (2 rounds of 128). grid (16,32,2)=1024 -> 4/CU.
__global__ __launch_bounds__(256, 4)
void atb(const unsigned short* __restrict__ e1T, const unsigned short* __restrict__ e2T,
         const unsigned short* __restrict__ xT, float* __restrict__ P_T)
{
  __shared__ __align__(16) unsigned short smA[64 * 136];  // [m][j]
  __shared__ __align__(16) unsigned short smB[64 * 136];  // [n][j]
  const int T = threadIdx.x, lane = T & 63, wv = T >> 6;
  const int q = lane >> 4, r = lane & 15;
  const int m0 = (blockIdx.x >> 2) * 64, n0 = (blockIdx.x & 3) * 64;
  const int y = blockIdx.y, z = blockIdx.z;
  const int j0 = y * (NE / NSPLIT);
  const unsigned short* E = z ? e2T : e1T;
  float* P = P_T + (size_t)(z * NSPLIT + y) * 65536;

  floatx4 acc[4];
#pragma unroll
  for (int j = 0; j < 4; ++j) acc[j] = (floatx4){0.f, 0.f, 0.f, 0.f};

  for (int jc = 0; jc < NE / NSPLIT; jc += 128) {
#pragma unroll
    for (int p = 0; p < 4; ++p) {
      const int id = p * 256 + T, mm = id >> 4, j8 = (id & 15) * 8;
      *(short8*)&smA[mm * 136 + j8] =
          *(const short8*)&E[(size_t)(m0 + mm) * NE + j0 + jc + j8];
      *(short8*)&smB[mm * 136 + j8] =
          *(const short8*)&xT[(size_t)(n0 + mm) * NE + j0 + jc + j8];
    }
    __syncthreads();
#pragma unroll
    for (int ks = 0; ks < 4; ++ks) {
      short8 af = *(const short8*)&smA[(wv * 16 + r) * 136 + ks * 32 + q * 8];
#pragma unroll
      for (int j = 0; j < 4; ++j) {
        short8 bf = *(const short8*)&smB[(j * 16 + r) * 136 + ks * 32 + q * 8];
        acc[j] = mfma_bf16(af, bf, acc[j]);
      }
    }
    __syncthreads();
  }
#pragma unroll
  for (int j = 0; j < 4; ++j) {
    const int n = n0 + j * 16 + r;
    const int m = m0 + wv * 16 + q * 4;
    *(floatx4*)&P[(size_t)n * DD + m] = acc[j];
  }
}

// ---------------------------------------------------------------------------
// K3: G_T[z][n][m] = sum_y P. 16 MB coalesced read, 128 blocks x 256 thr.
__global__ void reduce_g(const float* __restrict__ P_T, float* __restrict__ G_T) {
  int idx = blockIdx.x * 256 + threadIdx.x;        // 0..32767 floatx4
  int z = idx >> 14, off = idx & 16383;
  const floatx4* Pp = (const floatx4*)P_T;
  floatx4 s = (floatx4){0.f, 0.f, 0.f, 0.f};
#pragma unroll
  for (int y = 0; y < NSPLIT; ++y)
    s += Pp[(size_t)(z * NSPLIT + y) * 16384 + off];
  ((floatx4*)G_T)[idx] = s;
}

// ---------------------------------------------------------------------------
// K4: Ht_z = H_z^T, H_z = (G_z/256) @ W3seg_z. 64x64 tiles, grid (16,1,2).
__global__ __launch_bounds__(256, 2)
void h_mfma(const float* __restrict__ G_T, const float* __restrict__ W3,
            unsigned short* __restrict__ H1t, unsigned short* __restrict__ H2t)
{
  __shared__ __align__(16) unsigned short smA[64 * 136];
  __shared__ __align__(16) unsigned short smB[64 * 136];
  const int T = threadIdx.x, lane = T & 63, wv = T >> 6;
  const int q = lane >> 4, r = lane & 15;
  const int z = blockIdx.z;
  const int me0 = (blockIdx.x >> 2) * 64, m30 = (blockIdx.x & 3) * 64;
  const float* G = G_T + (size_t)z * 65536;
  unsigned short* Ht = z ? H2t : H1t;
  const int woff = 256 + z * 256;

  floatx4 acc[4];
#pragma unroll
  for (int j = 0; j < 4; ++j) acc[j] = (floatx4){0.f, 0.f, 0.f, 0.f};

  for (int lc = 0; lc < 256; lc += 128) {
#pragma unroll
    for (int p = 0; p < 2; ++p) {
      const int id = p * 256 + T, lb = id >> 4, e4 = id & 15;
      floatx4 grow[4], wrow[4];
#pragma unroll
      for (int i = 0; i < 4; ++i) {
        grow[i] = *(const floatx4*)&G[(size_t)(lc + lb * 4 + i) * DD + me0 + e4 * 4];
        wrow[i] = *(const floatx4*)&W3[(size_t)(woff + lc + lb * 4 + i) * DD + m30 + e4 * 4];
      }
#pragma unroll
      for (int s4 = 0; s4 < 4; ++s4) {
        const int c = (s4 + e4) & 3;
        short4v ga = {(short)f2bf(grow[0][c] * 0.00390625f),
                      (short)f2bf(grow[1][c] * 0.00390625f),
                      (short)f2bf(grow[2][c] * 0.00390625f),
                      (short)f2bf(grow[3][c] * 0.00390625f)};
        short4v wa = {(short)f2bf(wrow[0][c]), (short)f2bf(wrow[1][c]),
                      (short)f2bf(wrow[2][c]), (short)f2bf(wrow[3][c])};
        *(short4v*)&smA[(e4 * 4 + c) * 136 + lb * 4] = ga;
        *(short4v*)&smB[(e4 * 4 + c) * 136 + lb * 4] = wa;
      }
    }
    __syncthreads();
#pragma unroll
    for (int ks = 0; ks < 4; ++ks) {
      short8 af = *(const short8*)&smA[(wv * 16 + r) * 136 + ks * 32 + q * 8];
#pragma unroll
      for (int j = 0; j < 4; ++j) {
        short8 bf = *(const short8*)&smB[(j * 16 + r) * 136 + ks * 32 + q * 8];
        acc[j] = mfma_bf16(af, bf, acc[j]);
      }
    }
    __syncthreads();
  }
#pragma unroll
  for (int j = 0; j < 4; ++j) {
    const int m3 = m30 + j * 16 + r;
    const int me = me0 + wv * 16 + q * 4;
    short4v v;
#pragma unroll
    for (int i = 0; i < 4; ++i) v[i] = (short)f2bf(acc[j][i]);
    *(short4v*)&Ht[(size_t)m3 * DD + me] = v;
  }
}

// ---------------------------------------------------------------------------
// K5: out = relu(x@W3a + e1@H1 + e2@H2 + b3), fp32. Tile 64x64, BK=128,
// 3 segs x 2 rounds. grid (4,128)=512.
__global__ __launch_bounds__(256, 4)
void out_gemm(const float* __restrict__ x,
              const unsigned short* __restrict__ e1, const unsigned short* __restrict__ e2,
              const float* __restrict__ W3,
              const unsigned short* __restrict__ H1t, const unsigned short* __restrict__ H2t,
              const float* __restrict__ b3, float* __restrict__ out)
{
  __shared__ __align__(16) unsigned short smA[64 * 136];
  __shared__ __align__(16) unsigned short smB[64 * 136];
  const int T = threadIdx.x, lane = T & 63, wv = T >> 6;
  const int q = lane >> 4, r = lane & 15;
  const int col0 = blockIdx.x * 64, row0 = blockIdx.y * 64;

  floatx4 acc[4];
#pragma unroll
  for (int j = 0; j < 4; ++j) acc[j] = (floatx4){0.f, 0.f, 0.f, 0.f};

  for (int s = 0; s < 3; ++s) {
    for (int kc = 0; kc < 256; kc += 128) {
      if (s == 0) {
#pragma unroll
        for (int p = 0; p < 8; ++p) {
          const int id = p * 256 + T, rr = id >> 5, k4 = (id & 31) * 4;
          floatx4 v = *(const floatx4*)&x[(size_t)(row0 + rr) * DD + kc + k4];
          short4v sv;
#pragma unroll
          for (int c = 0; c < 4; ++c) sv[c] = (short)f2bf(v[c]);
          *(short4v*)&smA[rr * 136 + k4] = sv;
        }
#pragma unroll
        for (int p = 0; p < 2; ++p) {
          const int id = p * 256 + T, kb = id >> 4, n4 = id & 15;
          floatx4 wrow[4];
#pragma unroll
          for (int i = 0; i < 4; ++i)
            wrow[i] = *(const floatx4*)&W3[(size_t)(kc + kb * 4 + i) * DD + col0 + n4 * 4];
#pragma unroll
          for (int s4 = 0; s4 < 4; ++s4) {
            const int c = (s4 + n4) & 3;
            short4v sv = {(short)f2bf(wrow[0][c]), (short)f2bf(wrow[1][c]),
                          (short)f2bf(wrow[2][c]), (short)f2bf(wrow[3][c])};
            *(short4v*)&smB[(n4 * 4 + c) * 136 + kb * 4] = sv;
          }
        }
      } else {
        const unsigned short* E = (s == 1) ? e1 : e2;
        const unsigned short* Hs = (s == 1) ? H1t : H2t;
#pragma unroll
        for (int p = 0; p < 4; ++p) {
          const int id = p * 256 + T, rr = id >> 4, j8 = (id & 15) * 8;
          *(short8*)&smA[rr * 136 + j8] =
              *(const short8*)&E[(size_t)(row0 + rr) * DD + kc + j8];
          *(short8*)&smB[rr * 136 + j8] =
              *(const short8*)&Hs[(size_t)(col0 + rr) * DD + kc + j8];
        }
      }
      __syncthreads();
#pragma unroll
      for (int ks = 0; ks < 4; ++ks) {
        short8 af = *(const short8*)&smA[(wv * 16 + r) * 136 + ks * 32 + q * 8];
#pragma unroll
        for (int j = 0; j < 4; ++j) {
          short8 bf = *(const short8*)&smB[(j * 16 + r) * 136 + ks * 32 + q * 8];
          acc[j] = mfma_bf16(af, bf, acc[j]);
        }
      }
      __syncthreads();
    }
  }
#pragma unroll
  for (int j = 0; j < 4; ++j) {
    const int col = col0 + j * 16 + r;
    const float bv = b3[col];
    const int rowb = row0 + wv * 16 + q * 4;
#pragma unroll
    for (int t = 0; t < 4; ++t)
      out[(size_t)(rowb + t) * DD + col] = fmaxf(acc[j][t] + bv, 0.0f);
  }
}

// ---------------------------------------------------------------------------
extern "C" void kernel_launch(void* const* d_in, const int* in_sizes, int n_in,
                              void* d_out, int out_size, void* d_ws, size_t ws_size,
                              hipStream_t stream) {
  (void)in_sizes; (void)n_in; (void)out_size; (void)ws_size;
  const float* x  = (const float*)d_in[3];
  const float* W1 = (const float*)d_in[5];
  const float* b1 = (const float*)d_in[6];
  const float* W2 = (const float*)d_in[7];
  const float* b2 = (const float*)d_in[8];
  const float* W3 = (const float*)d_in[9];
  const float* b3 = (const float*)d_in[10];
  float* out = (float*)d_out;

  char* ws = (char*)d_ws;
  const size_t MB = 1u << 20;
  const size_t KB = 1u << 10;
  unsigned short* e1  = (unsigned short*)ws;                          // 4 MB
  unsigned short* e2  = (unsigned short*)(ws + 4 * MB);               // 4 MB
  unsigned short* e1T = (unsigned short*)(ws + 8 * MB);               // 4 MB
  unsigned short* e2T = (unsigned short*)(ws + 12 * MB);              // 4 MB
  unsigned short* xT  = (unsigned short*)(ws + 16 * MB);              // 4 MB
  unsigned short* H1t = (unsigned short*)(ws + 20 * MB);              // 128 KB
  unsigned short* H2t = (unsigned short*)(ws + 20 * MB + 128 * KB);   // 128 KB
  float* G_T          = (float*)(ws + 20 * MB + 256 * KB);            // 512 KB
  float* P_T          = (float*)(ws + 21 * MB);                       // 16 MB

  e_gemm<<<dim3(4, 128), 256, 0, stream>>>(x, W1, b1, W2, b2, e1, e2, e1T, e2T, xT);
  atb<<<dim3(16, NSPLIT, 2), 256, 0, stream>>>(e1T, e2T, xT, P_T);
  reduce_g<<<128, 256, 0, stream>>>(P_T, G_T);
  h_mfma<<<dim3(16, 1, 2), 256, 0, stream>>>(G_T, W3, H1t, H2t);
  out_gemm<<<dim3(4, 128), 256, 0, stream>>>(x, e1, e2, W3, H1t, H2t, b3, out);
}

// Round 11
// 126.009 us; speedup vs baseline: 1.4704x; 1.0693x over previous
//
#include <hip/hip_runtime.h>

#define NE 8192
#define DD 256
#define NSPLIT 32

typedef __attribute__((ext_vector_type(8))) short short8;
typedef __attribute__((ext_vector_type(4))) short short4v;
typedef __attribute__((ext_vector_type(8))) __bf16 bf16x8;
typedef __attribute__((ext_vector_type(4))) float floatx4;

__device__ __forceinline__ unsigned short f2bf(float f) {
  union { float f; unsigned int i; } v; v.f = f;
  unsigned int r = v.i + 0x7fffu + ((v.i >> 16) & 1u);
  return (unsigned short)(r >> 16);
}

__device__ __forceinline__ floatx4 mfma_bf16(short8 a, short8 b, floatx4 c) {
  return __builtin_amdgcn_mfma_f32_16x16x32_bf16(
      __builtin_bit_cast(bf16x8, a), __builtin_bit_cast(bf16x8, b), c, 0, 0, 0);
}

// ---------------------------------------------------------------------------
// K0: conversions. [0,1024): x->xb straight. [1024,1536): x->xT 64x64 tiles.
// [1536,1552) W1->W1t, [1552,1568) W2->W2t, [1568,1584) W3a->W3t0 (transposed).
__device__ __forceinline__ void tcvt_tile(const float* __restrict__ src, int C,
                                          unsigned short* __restrict__ dst, int R,
                                          int r0, int c0, int tid) {
  __shared__ float ls[64][68];
  const int rr = tid >> 4;
  const int c4 = (tid & 15) * 4;
#pragma unroll
  for (int k = 0; k < 4; ++k)
    *(floatx4*)&ls[rr + k * 16][c4] =
        *(const floatx4*)&src[(size_t)(r0 + rr + k * 16) * C + c0 + c4];
  __syncthreads();
  const int cc = tid >> 2;
  const int rb = (tid & 3) * 16;
  short8 o0, o1;
#pragma unroll
  for (int i = 0; i < 8; ++i) {
    o0[i] = (short)f2bf(ls[rb + i][cc]);
    o1[i] = (short)f2bf(ls[rb + 8 + i][cc]);
  }
  unsigned short* dp = &dst[(size_t)(c0 + cc) * R + r0 + rb];
  *(short8*)dp = o0;
  *(short8*)(dp + 8) = o1;
}

__global__ void cvt_all(const float* __restrict__ x, unsigned short* __restrict__ xb,
                        unsigned short* __restrict__ xT,
                        const float* __restrict__ W1, unsigned short* __restrict__ W1t,
                        const float* __restrict__ W2, unsigned short* __restrict__ W2t,
                        const float* __restrict__ W3, unsigned short* __restrict__ W3t0) {
  const int b = blockIdx.x, tid = threadIdx.x;
  if (b < 1024) {
    int i = b * 256 + tid;
    floatx4 a = ((const floatx4*)x)[2 * i];
    floatx4 c = ((const floatx4*)x)[2 * i + 1];
    short8 o;
#pragma unroll
    for (int k = 0; k < 4; ++k) { o[k] = (short)f2bf(a[k]); o[4 + k] = (short)f2bf(c[k]); }
    ((short8*)xb)[i] = o;
  } else if (b < 1536) {
    int t = b - 1024;
    tcvt_tile(x, DD, xT, NE, (t >> 2) * 64, (t & 3) * 64, tid);
  } else if (b < 1552) {
    int t = b - 1536;
    tcvt_tile(W1, DD, W1t, DD, (t >> 2) * 64, (t & 3) * 64, tid);
  } else if (b < 1568) {
    int t = b - 1552;
    tcvt_tile(W2, DD, W2t, DD, (t >> 2) * 64, (t & 3) * 64, tid);
  } else {
    int t = b - 1568;
    tcvt_tile(W3, DD, W3t0, DD, (t >> 2) * 64, (t & 3) * 64, tid);
  }
}

// ---------------------------------------------------------------------------
// K1: e1 AND e2 from one block (xb staged once, two W^T slabs, all bf16).
// Tile 64x64, BK=128 (2 rounds). grid (4,128)=512, LDS 52,224 B -> 3/CU.
__global__ __launch_bounds__(256, 3)
void e_gemm(const unsigned short* __restrict__ xb,
            const unsigned short* __restrict__ W1t, const float* __restrict__ b1,
            const unsigned short* __restrict__ W2t, const float* __restrict__ b2,
            unsigned short* __restrict__ e1, unsigned short* __restrict__ e2,
            unsigned short* __restrict__ e1T, unsigned short* __restrict__ e2T)
{
  __shared__ __align__(16) unsigned short smA[64 * 136];
  __shared__ __align__(16) unsigned short smB1[64 * 136];
  __shared__ __align__(16) unsigned short smB2[64 * 136];
  const int T = threadIdx.x, lane = T & 63, wv = T >> 6;
  const int q = lane >> 4, r = lane & 15;
  const int col0 = blockIdx.x * 64, row0 = blockIdx.y * 64;

  floatx4 acc1[4], acc2[4];
#pragma unroll
  for (int j = 0; j < 4; ++j) {
    acc1[j] = (floatx4){0.f, 0.f, 0.f, 0.f};
    acc2[j] = (floatx4){0.f, 0.f, 0.f, 0.f};
  }

  for (int kc = 0; kc < 256; kc += 128) {
#pragma unroll
    for (int p = 0; p < 4; ++p) {
      const int id = p * 256 + T, rr = id >> 4, k8 = (id & 15) * 8;
      *(short8*)&smA[rr * 136 + k8] =
          *(const short8*)&xb[(size_t)(row0 + rr) * DD + kc + k8];
      *(short8*)&smB1[rr * 136 + k8] =
          *(const short8*)&W1t[(size_t)(col0 + rr) * DD + kc + k8];
      *(short8*)&smB2[rr * 136 + k8] =
          *(const short8*)&W2t[(size_t)(col0 + rr) * DD + kc + k8];
    }
    __syncthreads();
#pragma unroll
    for (int ks = 0; ks < 4; ++ks) {
      short8 af = *(const short8*)&smA[(wv * 16 + r) * 136 + ks * 32 + q * 8];
#pragma unroll
      for (int j = 0; j < 4; ++j) {
        short8 b1f = *(const short8*)&smB1[(j * 16 + r) * 136 + ks * 32 + q * 8];
        short8 b2f = *(const short8*)&smB2[(j * 16 + r) * 136 + ks * 32 + q * 8];
        acc1[j] = mfma_bf16(af, b1f, acc1[j]);
        acc2[j] = mfma_bf16(af, b2f, acc2[j]);
      }
    }
    __syncthreads();
  }

#pragma unroll
  for (int j = 0; j < 4; ++j) {
    const int col = col0 + j * 16 + r;
    const int rowb = row0 + wv * 16 + q * 4;
    const float b1v = b1[col], b2v = b2[col];
    short4v t1, t2;
#pragma unroll
    for (int t = 0; t < 4; ++t) {
      unsigned short h1 = f2bf(fmaxf(acc1[j][t] + b1v, 0.0f));
      unsigned short h2 = f2bf(fmaxf(acc2[j][t] + b2v, 0.0f));
      t1[t] = (short)h1; t2[t] = (short)h2;
      e1[(size_t)(rowb + t) * DD + col] = h1;
      e2[(size_t)(rowb + t) * DD + col] = h2;
    }
    *(short4v*)&e1T[(size_t)col * NE + rowb] = t1;
    *(short4v*)&e2T[(size_t)col * NE + rowb] = t2;
  }
}

// ---------------------------------------------------------------------------
// K2: split-K partials P[(z*32+y)][n][m] of G = e_z^T @ x.
// Tile 128(m) x 64(n), j-span 256 (2 rounds of 128). grid (8,32,2)=512, 3/CU.
__global__ __launch_bounds__(256, 3)
void atb(const unsigned short* __restrict__ e1T, const unsigned short* __restrict__ e2T,
         const unsigned short* __restrict__ xT, float* __restrict__ P_T)
{
  __shared__ __align__(16) unsigned short smA[128 * 136];  // [m][j]
  __shared__ __align__(16) unsigned short smB[64 * 136];   // [n][j]
  const int T = threadIdx.x, lane = T & 63, wv = T >> 6;
  const int q = lane >> 4, r = lane & 15;
  const int m0 = (blockIdx.x >> 2) * 128, n0 = (blockIdx.x & 3) * 64;
  const int y = blockIdx.y, z = blockIdx.z;
  const int j0 = y * (NE / NSPLIT);
  const unsigned short* E = z ? e2T : e1T;
  float* P = P_T + (size_t)(z * NSPLIT + y) * 65536;

  floatx4 acc[2][4];
#pragma unroll
  for (int i = 0; i < 2; ++i)
#pragma unroll
    for (int j = 0; j < 4; ++j) acc[i][j] = (floatx4){0.f, 0.f, 0.f, 0.f};

  for (int jc = 0; jc < NE / NSPLIT; jc += 128) {
#pragma unroll
    for (int p = 0; p < 8; ++p) {
      const int id = p * 256 + T, mm = id >> 4, j8 = (id & 15) * 8;
      *(short8*)&smA[mm * 136 + j8] =
          *(const short8*)&E[(size_t)(m0 + mm) * NE + j0 + jc + j8];
    }
#pragma unroll
    for (int p = 0; p < 4; ++p) {
      const int id = p * 256 + T, nn = id >> 4, j8 = (id & 15) * 8;
      *(short8*)&smB[nn * 136 + j8] =
          *(const short8*)&xT[(size_t)(n0 + nn) * NE + j0 + jc + j8];
    }
    __syncthreads();
#pragma unroll
    for (int ks = 0; ks < 4; ++ks) {
      short8 af[2], bf[4];
#pragma unroll
      for (int i = 0; i < 2; ++i)
        af[i] = *(const short8*)&smA[(wv * 32 + i * 16 + r) * 136 + ks * 32 + q * 8];
#pragma unroll
      for (int j = 0; j < 4; ++j)
        bf[j] = *(const short8*)&smB[(j * 16 + r) * 136 + ks * 32 + q * 8];
#pragma unroll
      for (int i = 0; i < 2; ++i)
#pragma unroll
        for (int j = 0; j < 4; ++j)
          acc[i][j] = mfma_bf16(af[i], bf[j], acc[i][j]);
    }
    __syncthreads();
  }
#pragma unroll
  for (int i = 0; i < 2; ++i)
#pragma unroll
    for (int j = 0; j < 4; ++j) {
      const int n = n0 + j * 16 + r;
      const int m = m0 + wv * 32 + i * 16 + q * 4;
      *(floatx4*)&P[(size_t)n * DD + m] = acc[i][j];
    }
}

// ---------------------------------------------------------------------------
// K3: G_T[z][n][m] = sum_y P. 16 MB coalesced, 128 blocks x 256 thr.
__global__ void reduce_g(const float* __restrict__ P_T, float* __restrict__ G_T) {
  int idx = blockIdx.x * 256 + threadIdx.x;
  int z = idx >> 14, off = idx & 16383;
  const floatx4* Pp = (const floatx4*)P_T;
  floatx4 s = (floatx4){0.f, 0.f, 0.f, 0.f};
#pragma unroll
  for (int y = 0; y < NSPLIT; ++y)
    s += Pp[(size_t)(z * NSPLIT + y) * 16384 + off];
  ((floatx4*)G_T)[idx] = s;
}

// ---------------------------------------------------------------------------
// K4: Ht_z = H_z^T, H_z = (G_z/256) @ W3seg_z. 64x64 tiles, grid (16,1,2).
__global__ __launch_bounds__(256, 2)
void h_mfma(const float* __restrict__ G_T, const float* __restrict__ W3,
            unsigned short* __restrict__ H1t, unsigned short* __restrict__ H2t)
{
  __shared__ __align__(16) unsigned short smA[64 * 136];
  __shared__ __align__(16) unsigned short smB[64 * 136];
  const int T = threadIdx.x, lane = T & 63, wv = T >> 6;
  const int q = lane >> 4, r = lane & 15;
  const int z = blockIdx.z;
  const int me0 = (blockIdx.x >> 2) * 64, m30 = (blockIdx.x & 3) * 64;
  const float* G = G_T + (size_t)z * 65536;
  unsigned short* Ht = z ? H2t : H1t;
  const int woff = 256 + z * 256;

  floatx4 acc[4];
#pragma unroll
  for (int j = 0; j < 4; ++j) acc[j] = (floatx4){0.f, 0.f, 0.f, 0.f};

  for (int lc = 0; lc < 256; lc += 128) {
#pragma unroll
    for (int p = 0; p < 2; ++p) {
      const int id = p * 256 + T, lb = id >> 4, e4 = id & 15;
      floatx4 grow[4], wrow[4];
#pragma unroll
      for (int i = 0; i < 4; ++i) {
        grow[i] = *(const floatx4*)&G[(size_t)(lc + lb * 4 + i) * DD + me0 + e4 * 4];
        wrow[i] = *(const floatx4*)&W3[(size_t)(woff + lc + lb * 4 + i) * DD + m30 + e4 * 4];
      }
#pragma unroll
      for (int s4 = 0; s4 < 4; ++s4) {
        const int c = (s4 + e4) & 3;
        short4v ga = {(short)f2bf(grow[0][c] * 0.00390625f),
                      (short)f2bf(grow[1][c] * 0.00390625f),
                      (short)f2bf(grow[2][c] * 0.00390625f),
                      (short)f2bf(grow[3][c] * 0.00390625f)};
        short4v wa = {(short)f2bf(wrow[0][c]), (short)f2bf(wrow[1][c]),
                      (short)f2bf(wrow[2][c]), (short)f2bf(wrow[3][c])};
        *(short4v*)&smA[(e4 * 4 + c) * 136 + lb * 4] = ga;
        *(short4v*)&smB[(e4 * 4 + c) * 136 + lb * 4] = wa;
      }
    }
    __syncthreads();
#pragma unroll
    for (int ks = 0; ks < 4; ++ks) {
      short8 af = *(const short8*)&smA[(wv * 16 + r) * 136 + ks * 32 + q * 8];
#pragma unroll
      for (int j = 0; j < 4; ++j) {
        short8 bf = *(const short8*)&smB[(j * 16 + r) * 136 + ks * 32 + q * 8];
        acc[j] = mfma_bf16(af, bf, acc[j]);
      }
    }
    __syncthreads();
  }
#pragma unroll
  for (int j = 0; j < 4; ++j) {
    const int m3 = m30 + j * 16 + r;
    const int me = me0 + wv * 16 + q * 4;
    short4v v;
#pragma unroll
    for (int i = 0; i < 4; ++i) v[i] = (short)f2bf(acc[j][i]);
    *(short4v*)&Ht[(size_t)m3 * DD + me] = v;
  }
}

// ---------------------------------------------------------------------------
// K5: out = relu(xb@W3t0^T + e1@H1 + e2@H2 + b3), fp32. All-bf16 uniform
// 6-round loop (3 segs x BK=128). Tile 64x64, grid (4,128)=512, LDS 34.8 KB.
__global__ __launch_bounds__(256, 3)
void out_gemm(const unsigned short* __restrict__ xb,
              const unsigned short* __restrict__ e1, const unsigned short* __restrict__ e2,
              const unsigned short* __restrict__ W3t0,
              const unsigned short* __restrict__ H1t, const unsigned short* __restrict__ H2t,
              const float* __restrict__ b3, float* __restrict__ out)
{
  __shared__ __align__(16) unsigned short smA[64 * 136];
  __shared__ __align__(16) unsigned short smB[64 * 136];
  const int T = threadIdx.x, lane = T & 63, wv = T >> 6;
  const int q = lane >> 4, r = lane & 15;
  const int col0 = blockIdx.x * 64, row0 = blockIdx.y * 64;

  floatx4 acc[4];
#pragma unroll
  for (int j = 0; j < 4; ++j) acc[j] = (floatx4){0.f, 0.f, 0.f, 0.f};

  const unsigned short* As[3] = {xb, e1, e2};
  const unsigned short* Bs[3] = {W3t0, H1t, H2t};

  for (int rd = 0; rd < 6; ++rd) {
    const int s = rd >> 1, kc = (rd & 1) * 128;
    const unsigned short* A = As[s];
    const unsigned short* B = Bs[s];
#pragma unroll
    for (int p = 0; p < 4; ++p) {
      const int id = p * 256 + T, rr = id >> 4, k8 = (id & 15) * 8;
      *(short8*)&smA[rr * 136 + k8] =
          *(const short8*)&A[(size_t)(row0 + rr) * DD + kc + k8];
      *(short8*)&smB[rr * 136 + k8] =
          *(const short8*)&B[(size_t)(col0 + rr) * DD + kc + k8];
    }
    __syncthreads();
#pragma unroll
    for (int ks = 0; ks < 4; ++ks) {
      short8 af = *(const short8*)&smA[(wv * 16 + r) * 136 + ks * 32 + q * 8];
#pragma unroll
      for (int j = 0; j < 4; ++j) {
        short8 bf = *(const short8*)&smB[(j * 16 + r) * 136 + ks * 32 + q * 8];
        acc[j] = mfma_bf16(af, bf, acc[j]);
      }
    }
    __syncthreads();
  }
#pragma unroll
  for (int j = 0; j < 4; ++j) {
    const int col = col0 + j * 16 + r;
    const float bv = b3[col];
    const int rowb = row0 + wv * 16 + q * 4;
#pragma unroll
    for (int t = 0; t < 4; ++t)
      out[(size_t)(rowb + t) * DD + col] = fmaxf(acc[j][t] + bv, 0.0f);
  }
}

// ---------------------------------------------------------------------------
extern "C" void kernel_launch(void* const* d_in, const int* in_sizes, int n_in,
                              void* d_out, int out_size, void* d_ws, size_t ws_size,
                              hipStream_t stream) {
  (void)in_sizes; (void)n_in; (void)out_size; (void)ws_size;
  const float* x  = (const float*)d_in[3];
  const float* W1 = (const float*)d_in[5];
  const float* b1 = (const float*)d_in[6];
  const float* W2 = (const float*)d_in[7];
  const float* b2 = (const float*)d_in[8];
  const float* W3 = (const float*)d_in[9];
  const float* b3 = (const float*)d_in[10];
  float* out = (float*)d_out;

  char* ws = (char*)d_ws;
  const size_t MB = 1u << 20;
  const size_t KB = 1u << 10;
  unsigned short* xb   = (unsigned short*)ws;                          // 4 MB
  unsigned short* xT   = (unsigned short*)(ws + 4 * MB);               // 4 MB
  unsigned short* e1   = (unsigned short*)(ws + 8 * MB);               // 4 MB
  unsigned short* e2   = (unsigned short*)(ws + 12 * MB);              // 4 MB
  unsigned short* e1T  = (unsigned short*)(ws + 16 * MB);              // 4 MB
  unsigned short* e2T  = (unsigned short*)(ws + 20 * MB);              // 4 MB
  unsigned short* W1t  = (unsigned short*)(ws + 24 * MB);              // 128 KB
  unsigned short* W2t  = (unsigned short*)(ws + 24 * MB + 128 * KB);   // 128 KB
  unsigned short* W3t0 = (unsigned short*)(ws + 24 * MB + 256 * KB);   // 128 KB
  unsigned short* H1t  = (unsigned short*)(ws + 24 * MB + 384 * KB);   // 128 KB
  unsigned short* H2t  = (unsigned short*)(ws + 24 * MB + 512 * KB);   // 128 KB
  float* G_T           = (float*)(ws + 24 * MB + 640 * KB);            // 512 KB
  float* P_T           = (float*)(ws + 25 * MB);                       // 16 MB

  cvt_all<<<1584, 256, 0, stream>>>(x, xb, xT, W1, W1t, W2, W2t, W3, W3t0);
  e_gemm<<<dim3(4, 128), 256, 0, stream>>>(xb, W1t, b1, W2t, b2, e1, e2, e1T, e2T);
  atb<<<dim3(8, NSPLIT, 2), 256, 0, stream>>>(e1T, e2T, xT, P_T);
  reduce_g<<<128, 256, 0, stream>>>(P_T, G_T);
  h_mfma<<<dim3(16, 1, 2), 256, 0, stream>>>(G_T, W3, H1t, H2t);
  out_gemm<<<dim3(4, 128), 256, 0, stream>>>(xb, e1, e2, W3t0, H1t, H2t, b3, out);
}

// Round 16
// 122.115 us; speedup vs baseline: 1.5173x; 1.0319x over previous
//
// MPModule fused pipeline, round 15 (identical experiment to rounds 11-14).
// Structure: cvt_all -> e_gemm -> atb -> reduce_g -> h_mfma -> out_gemm.
// All GEMM K-loops are pure bf16 short8 loads -> LDS -> MFMA with register
// prefetch of the next round's operands issued immediately after the barrier.
#include <hip/hip_runtime.h>

#define NE 8192
#define DD 256
#define NSPLIT 16

typedef __attribute__((ext_vector_type(8))) short short8;
typedef __attribute__((ext_vector_type(4))) short short4v;
typedef __attribute__((ext_vector_type(8))) __bf16 bf16x8;
typedef __attribute__((ext_vector_type(4))) float floatx4;

__device__ __forceinline__ unsigned short f2bf(float f) {
  union { float f; unsigned int i; } v; v.f = f;
  unsigned int r = v.i + 0x7fffu + ((v.i >> 16) & 1u);
  return (unsigned short)(r >> 16);
}

__device__ __forceinline__ floatx4 mfma_bf16(short8 a, short8 b, floatx4 c) {
  return __builtin_amdgcn_mfma_f32_16x16x32_bf16(
      __builtin_bit_cast(bf16x8, a), __builtin_bit_cast(bf16x8, b), c, 0, 0, 0);
}

// ---------------------------------------------------------------------------
// K0: conversions, x read ONCE. Blocks [0,512): one 64x64 x-tile -> xb
// (row-major bf16) AND xT (transposed bf16). [512,560): W1/W2/W3a transpose.
__device__ __forceinline__ void tcvt_tile(float* ls,
                                          const float* __restrict__ src, int C,
                                          unsigned short* __restrict__ dst, int R,
                                          int r0, int c0, int tid) {
  const int rr = tid >> 4, c4 = (tid & 15) * 4;
#pragma unroll
  for (int k = 0; k < 4; ++k)
    *(floatx4*)&ls[(rr + k * 16) * 68 + c4] =
        *(const floatx4*)&src[(size_t)(r0 + rr + k * 16) * C + c0 + c4];
  __syncthreads();
  const int cc = tid >> 2, rb = (tid & 3) * 16;
  short8 o0, o1;
#pragma unroll
  for (int i = 0; i < 8; ++i) {
    o0[i] = (short)f2bf(ls[(rb + i) * 68 + cc]);
    o1[i] = (short)f2bf(ls[(rb + 8 + i) * 68 + cc]);
  }
  unsigned short* dp = &dst[(size_t)(c0 + cc) * R + r0 + rb];
  *(short8*)dp = o0;
  *(short8*)(dp + 8) = o1;
}

__global__ void cvt_all(const float* __restrict__ x, unsigned short* __restrict__ xb,
                        unsigned short* __restrict__ xT,
                        const float* __restrict__ W1, unsigned short* __restrict__ W1t,
                        const float* __restrict__ W2, unsigned short* __restrict__ W2t,
                        const float* __restrict__ W3, unsigned short* __restrict__ W3t0) {
  __shared__ float ls[64 * 68];
  const int b = blockIdx.x, tid = threadIdx.x;
  if (b < 512) {
    const int r0 = (b >> 2) * 64, c0 = (b & 3) * 64;
    const int rr = tid >> 4, c4 = (tid & 15) * 4;
#pragma unroll
    for (int k = 0; k < 4; ++k) {
      floatx4 v = *(const floatx4*)&x[(size_t)(r0 + rr + k * 16) * DD + c0 + c4];
      *(floatx4*)&ls[(rr + k * 16) * 68 + c4] = v;
      short4v s;
#pragma unroll
      for (int c = 0; c < 4; ++c) s[c] = (short)f2bf(v[c]);
      *(short4v*)&xb[(size_t)(r0 + rr + k * 16) * DD + c0 + c4] = s;
    }
    __syncthreads();
    const int cc = tid >> 2, rb = (tid & 3) * 16;
    short8 o0, o1;
#pragma unroll
    for (int i = 0; i < 8; ++i) {
      o0[i] = (short)f2bf(ls[(rb + i) * 68 + cc]);
      o1[i] = (short)f2bf(ls[(rb + 8 + i) * 68 + cc]);
    }
    unsigned short* dp = &xT[(size_t)(c0 + cc) * NE + r0 + rb];
    *(short8*)dp = o0;
    *(short8*)(dp + 8) = o1;
  } else {
    int t = b - 512;
    const float* src = (t < 16) ? W1 : ((t < 32) ? W2 : W3);
    unsigned short* dst = (t < 16) ? W1t : ((t < 32) ? W2t : W3t0);
    t &= 15;
    tcvt_tile(ls, src, DD, dst, DD, (t >> 2) * 64, (t & 3) * 64, tid);
  }
}

// ---------------------------------------------------------------------------
// K1: e1 AND e2 from one block, reg-prefetch pipelined. Tile 64x64, BK=128
// (2 rounds). grid (4,128)=512, LDS 52,224 B -> 3 blocks/CU.
__global__ __launch_bounds__(256, 3)
void e_gemm(const unsigned short* __restrict__ xb,
            const unsigned short* __restrict__ W1t, const float* __restrict__ b1,
            const unsigned short* __restrict__ W2t, const float* __restrict__ b2,
            unsigned short* __restrict__ e1, unsigned short* __restrict__ e2,
            unsigned short* __restrict__ e1T, unsigned short* __restrict__ e2T)
{
  __shared__ __align__(16) unsigned short smA[64 * 136];
  __shared__ __align__(16) unsigned short smB1[64 * 136];
  __shared__ __align__(16) unsigned short smB2[64 * 136];
  const int T = threadIdx.x, lane = T & 63, wv = T >> 6;
  const int q = lane >> 4, r = lane & 15;
  const int col0 = blockIdx.x * 64, row0 = blockIdx.y * 64;

  floatx4 acc1[4], acc2[4];
#pragma unroll
  for (int j = 0; j < 4; ++j) {
    acc1[j] = (floatx4){0.f, 0.f, 0.f, 0.f};
    acc2[j] = (floatx4){0.f, 0.f, 0.f, 0.f};
  }

  short8 pa[4], pb1[4], pb2[4];
#pragma unroll
  for (int p = 0; p < 4; ++p) {
    const int id = p * 256 + T, rr = id >> 4, k8 = (id & 15) * 8;
    pa[p]  = *(const short8*)&xb[(size_t)(row0 + rr) * DD + k8];
    pb1[p] = *(const short8*)&W1t[(size_t)(col0 + rr) * DD + k8];
    pb2[p] = *(const short8*)&W2t[(size_t)(col0 + rr) * DD + k8];
  }

  for (int kc = 0; kc < 256; kc += 128) {
#pragma unroll
    for (int p = 0; p < 4; ++p) {
      const int id = p * 256 + T, rr = id >> 4, k8 = (id & 15) * 8;
      *(short8*)&smA[rr * 136 + k8]  = pa[p];
      *(short8*)&smB1[rr * 136 + k8] = pb1[p];
      *(short8*)&smB2[rr * 136 + k8] = pb2[p];
    }
    __syncthreads();
    if (kc + 128 < 256) {
#pragma unroll
      for (int p = 0; p < 4; ++p) {
        const int id = p * 256 + T, rr = id >> 4, k8 = (id & 15) * 8;
        pa[p]  = *(const short8*)&xb[(size_t)(row0 + rr) * DD + kc + 128 + k8];
        pb1[p] = *(const short8*)&W1t[(size_t)(col0 + rr) * DD + kc + 128 + k8];
        pb2[p] = *(const short8*)&W2t[(size_t)(col0 + rr) * DD + kc + 128 + k8];
      }
    }
#pragma unroll
    for (int ks = 0; ks < 4; ++ks) {
      short8 af = *(const short8*)&smA[(wv * 16 + r) * 136 + ks * 32 + q * 8];
#pragma unroll
      for (int j = 0; j < 4; ++j) {
        short8 b1f = *(const short8*)&smB1[(j * 16 + r) * 136 + ks * 32 + q * 8];
        short8 b2f = *(const short8*)&smB2[(j * 16 + r) * 136 + ks * 32 + q * 8];
        acc1[j] = mfma_bf16(af, b1f, acc1[j]);
        acc2[j] = mfma_bf16(af, b2f, acc2[j]);
      }
    }
    __syncthreads();
  }

#pragma unroll
  for (int j = 0; j < 4; ++j) {
    const int col = col0 + j * 16 + r;
    const int rowb = row0 + wv * 16 + q * 4;
    const float b1v = b1[col], b2v = b2[col];
    short4v t1, t2;
#pragma unroll
    for (int t = 0; t < 4; ++t) {
      unsigned short h1 = f2bf(fmaxf(acc1[j][t] + b1v, 0.0f));
      unsigned short h2 = f2bf(fmaxf(acc2[j][t] + b2v, 0.0f));
      t1[t] = (short)h1; t2[t] = (short)h2;
      e1[(size_t)(rowb + t) * DD + col] = h1;
      e2[(size_t)(rowb + t) * DD + col] = h2;
    }
    *(short4v*)&e1T[(size_t)col * NE + rowb] = t1;
    *(short4v*)&e2T[(size_t)col * NE + rowb] = t2;
  }
}

// ---------------------------------------------------------------------------
// K2: split-K partials P[(z*16+y)][n][m] of G = eT x. Tile 64x64, j-span 512
// (4 rounds of 128), reg-prefetch. grid (16,16,2)=512 -> 4 blocks/CU.
__global__ __launch_bounds__(256, 4)
void atb(const unsigned short* __restrict__ e1T, const unsigned short* __restrict__ e2T,
         const unsigned short* __restrict__ xT, float* __restrict__ P_T)
{
  __shared__ __align__(16) unsigned short smA[64 * 136];  // [m][j]
  __shared__ __align__(16) unsigned short smB[64 * 136];  // [n][j]
  const int T = threadIdx.x, lane = T & 63, wv = T >> 6;
  const int q = lane >> 4, r = lane & 15;
  const int m0 = (blockIdx.x >> 2) * 64, n0 = (blockIdx.x & 3) * 64;
  const int y = blockIdx.y, z = blockIdx.z;
  const int j0 = y * (NE / NSPLIT);
  const unsigned short* E = z ? e2T : e1T;
  float* P = P_T + (size_t)(z * NSPLIT + y) * 65536;

  floatx4 acc[4];
#pragma unroll
  for (int j = 0; j < 4; ++j) acc[j] = (floatx4){0.f, 0.f, 0.f, 0.f};

  short8 pa[4], pb[4];
#pragma unroll
  for (int p = 0; p < 4; ++p) {
    const int id = p * 256 + T, mm = id >> 4, j8 = (id & 15) * 8;
    pa[p] = *(const short8*)&E[(size_t)(m0 + mm) * NE + j0 + j8];
    pb[p] = *(const short8*)&xT[(size_t)(n0 + mm) * NE + j0 + j8];
  }

  for (int jc = 0; jc < NE / NSPLIT; jc += 128) {
#pragma unroll
    for (int p = 0; p < 4; ++p) {
      const int id = p * 256 + T, mm = id >> 4, j8 = (id & 15) * 8;
      *(short8*)&smA[mm * 136 + j8] = pa[p];
      *(short8*)&smB[mm * 136 + j8] = pb[p];
    }
    __syncthreads();
    if (jc + 128 < NE / NSPLIT) {
#pragma unroll
      for (int p = 0; p < 4; ++p) {
        const int id = p * 256 + T, mm = id >> 4, j8 = (id & 15) * 8;
        pa[p] = *(const short8*)&E[(size_t)(m0 + mm) * NE + j0 + jc + 128 + j8];
        pb[p] = *(const short8*)&xT[(size_t)(n0 + mm) * NE + j0 + jc + 128 + j8];
      }
    }
#pragma unroll
    for (int ks = 0; ks < 4; ++ks) {
      short8 af = *(const short8*)&smA[(wv * 16 + r) * 136 + ks * 32 + q * 8];
#pragma unroll
      for (int j = 0; j < 4; ++j) {
        short8 bf = *(const short8*)&smB[(j * 16 + r) * 136 + ks * 32 + q * 8];
        acc[j] = mfma_bf16(af, bf, acc[j]);
      }
    }
    __syncthreads();
  }
#pragma unroll
  for (int j = 0; j < 4; ++j) {
    const int n = n0 + j * 16 + r;
    const int m = m0 + wv * 16 + q * 4;
    *(floatx4*)&P[(size_t)n * DD + m] = acc[j];
  }
}

// ---------------------------------------------------------------------------
// K3: G_T[z][n][m] = sum over y of P. 8 MB coalesced, 128 blocks x 256 thr.
__global__ void reduce_g(const float* __restrict__ P_T, float* __restrict__ G_T) {
  int idx = blockIdx.x * 256 + threadIdx.x;
  int z = idx >> 14, off = idx & 16383;
  const floatx4* Pp = (const floatx4*)P_T;
  floatx4 s = (floatx4){0.f, 0.f, 0.f, 0.f};
#pragma unroll
  for (int y = 0; y < NSPLIT; ++y)
    s += Pp[(size_t)(z * NSPLIT + y) * 16384 + off];
  ((floatx4*)G_T)[idx] = s;
}

// ---------------------------------------------------------------------------
// K4: Ht_z = transpose of H_z, H_z = (G_z/256) @ W3seg_z. 64x64 tiles,
// grid (16,1,2) on L2-hot G_T and W3.
__global__ __launch_bounds__(256, 2)
void h_mfma(const float* __restrict__ G_T, const float* __restrict__ W3,
            unsigned short* __restrict__ H1t, unsigned short* __restrict__ H2t)
{
  __shared__ __align__(16) unsigned short smA[64 * 136];
  __shared__ __align__(16) unsigned short smB[64 * 136];
  const int T = threadIdx.x, lane = T & 63, wv = T >> 6;
  const int q = lane >> 4, r = lane & 15;
  const int z = blockIdx.z;
  const int me0 = (blockIdx.x >> 2) * 64, m30 = (blockIdx.x & 3) * 64;
  const float* G = G_T + (size_t)z * 65536;
  unsigned short* Ht = z ? H2t : H1t;
  const int woff = 256 + z * 256;

  floatx4 acc[4];
#pragma unroll
  for (int j = 0; j < 4; ++j) acc[j] = (floatx4){0.f, 0.f, 0.f, 0.f};

  for (int lc = 0; lc < 256; lc += 128) {
#pragma unroll
    for (int p = 0; p < 2; ++p) {
      const int id = p * 256 + T, lb = id >> 4, e4 = id & 15;
      floatx4 grow[4], wrow[4];
#pragma unroll
      for (int i = 0; i < 4; ++i) {
        grow[i] = *(const floatx4*)&G[(size_t)(lc + lb * 4 + i) * DD + me0 + e4 * 4];
        wrow[i] = *(const floatx4*)&W3[(size_t)(woff + lc + lb * 4 + i) * DD + m30 + e4 * 4];
      }
#pragma unroll
      for (int s4 = 0; s4 < 4; ++s4) {
        const int c = (s4 + e4) & 3;
        short4v ga = {(short)f2bf(grow[0][c] * 0.00390625f),
                      (short)f2bf(grow[1][c] * 0.00390625f),
                      (short)f2bf(grow[2][c] * 0.00390625f),
                      (short)f2bf(grow[3][c] * 0.00390625f)};
        short4v wa = {(short)f2bf(wrow[0][c]), (short)f2bf(wrow[1][c]),
                      (short)f2bf(wrow[2][c]), (short)f2bf(wrow[3][c])};
        *(short4v*)&smA[(e4 * 4 + c) * 136 + lb * 4] = ga;
        *(short4v*)&smB[(e4 * 4 + c) * 136 + lb * 4] = wa;
      }
    }
    __syncthreads();
#pragma unroll
    for (int ks = 0; ks < 4; ++ks) {
      short8 af = *(const short8*)&smA[(wv * 16 + r) * 136 + ks * 32 + q * 8];
#pragma unroll
      for (int j = 0; j < 4; ++j) {
        short8 bf = *(const short8*)&smB[(j * 16 + r) * 136 + ks * 32 + q * 8];
        acc[j] = mfma_bf16(af, bf, acc[j]);
      }
    }
    __syncthreads();
  }
#pragma unroll
  for (int j = 0; j < 4; ++j) {
    const int m3 = m30 + j * 16 + r;
    const int me = me0 + wv * 16 + q * 4;
    short4v v;
#pragma unroll
    for (int i = 0; i < 4; ++i) v[i] = (short)f2bf(acc[j][i]);
    *(short4v*)&Ht[(size_t)m3 * DD + me] = v;
  }
}

// ---------------------------------------------------------------------------
// K5: out = relu(xb*W3a + e1*H1 + e2*H2 + b3), fp32 out. Uniform 6-round
// bf16 loop with reg-prefetch. Tile 64x64, grid (4,128)=512 -> 4 blocks/CU.
__global__ __launch_bounds__(256, 4)
void out_gemm(const unsigned short* __restrict__ xb,
              const unsigned short* __restrict__ e1, const unsigned short* __restrict__ e2,
              const unsigned short* __restrict__ W3t0,
              const unsigned short* __restrict__ H1t, const unsigned short* __restrict__ H2t,
              const float* __restrict__ b3, float* __restrict__ out)
{
  __shared__ __align__(16) unsigned short smA[64 * 136];
  __shared__ __align__(16) unsigned short smB[64 * 136];
  const int T = threadIdx.x, lane = T & 63, wv = T >> 6;
  const int q = lane >> 4, r = lane & 15;
  const int col0 = blockIdx.x * 64, row0 = blockIdx.y * 64;

  const unsigned short* As[3] = {xb, e1, e2};
  const unsigned short* Bs[3] = {W3t0, H1t, H2t};

  floatx4 acc[4];
#pragma unroll
  for (int j = 0; j < 4; ++j) acc[j] = (floatx4){0.f, 0.f, 0.f, 0.f};

  short8 qa[4], qb[4];
#pragma unroll
  for (int p = 0; p < 4; ++p) {
    const int id = p * 256 + T, rr = id >> 4, k8 = (id & 15) * 8;
    qa[p] = *(const short8*)&As[0][(size_t)(row0 + rr) * DD + k8];
    qb[p] = *(const short8*)&Bs[0][(size_t)(col0 + rr) * DD + k8];
  }

  for (int rd = 0; rd < 6; ++rd) {
#pragma unroll
    for (int p = 0; p < 4; ++p) {
      const int id = p * 256 + T, rr = id >> 4, k8 = (id & 15) * 8;
      *(short8*)&smA[rr * 136 + k8] = qa[p];
      *(short8*)&smB[rr * 136 + k8] = qb[p];
    }
    __syncthreads();
    if (rd + 1 < 6) {
      const int s = (rd + 1) >> 1, kc = ((rd + 1) & 1) * 128;
      const unsigned short* A = As[s];
      const unsigned short* B = Bs[s];
#pragma unroll
      for (int p = 0; p < 4; ++p) {
        const int id = p * 256 + T, rr = id >> 4, k8 = (id & 15) * 8;
        qa[p] = *(const short8*)&A[(size_t)(row0 + rr) * DD + kc + k8];
        qb[p] = *(const short8*)&B[(size_t)(col0 + rr) * DD + kc + k8];
      }
    }
#pragma unroll
    for (int ks = 0; ks < 4; ++ks) {
      short8 af = *(const short8*)&smA[(wv * 16 + r) * 136 + ks * 32 + q * 8];
#pragma unroll
      for (int j = 0; j < 4; ++j) {
        short8 bf = *(const short8*)&smB[(j * 16 + r) * 136 + ks * 32 + q * 8];
        acc[j] = mfma_bf16(af, bf, acc[j]);
      }
    }
    __syncthreads();
  }
#pragma unroll
  for (int j = 0; j < 4; ++j) {
    const int col = col0 + j * 16 + r;
    const float bv = b3[col];
    const int rowb = row0 + wv * 16 + q * 4;
#pragma unroll
    for (int t = 0; t < 4; ++t)
      out[(size_t)(rowb + t) * DD + col] = fmaxf(acc[j][t] + bv, 0.0f);
  }
}

// ---------------------------------------------------------------------------
extern "C" void kernel_launch(void* const* d_in, const int* in_sizes, int n_in,
                              void* d_out, int out_size, void* d_ws, size_t ws_size,
                              hipStream_t stream) {
  (void)in_sizes; (void)n_in; (void)out_size; (void)ws_size;
  const float* x  = (const float*)d_in[3];
  const float* W1 = (const float*)d_in[5];
  const float* b1 = (const float*)d_in[6];
  const float* W2 = (const float*)d_in[7];
  const float* b2 = (const float*)d_in[8];
  const float* W3 = (const float*)d_in[9];
  const float* b3 = (const float*)d_in[10];
  float* out = (float*)d_out;

  char* ws = (char*)d_ws;
  const size_t MB = 1u << 20;
  const size_t KB = 1u << 10;
  unsigned short* xb   = (unsigned short*)ws;                          // 4 MB
  unsigned short* xT   = (unsigned short*)(ws + 4 * MB);               // 4 MB
  unsigned short* e1   = (unsigned short*)(ws + 8 * MB);               // 4 MB
  unsigned short* e2   = (unsigned short*)(ws + 12 * MB);              // 4 MB
  unsigned short* e1T  = (unsigned short*)(ws + 16 * MB);              // 4 MB
  unsigned short* e2T  = (unsigned short*)(ws + 20 * MB);              // 4 MB
  unsigned short* W1t  = (unsigned short*)(ws + 24 * MB);              // 128 KB
  unsigned short* W2t  = (unsigned short*)(ws + 24 * MB + 128 * KB);   // 128 KB
  unsigned short* W3t0 = (unsigned short*)(ws + 24 * MB + 256 * KB);   // 128 KB
  unsigned short* H1t  = (unsigned short*)(ws + 24 * MB + 384 * KB);   // 128 KB
  unsigned short* H2t  = (unsigned short*)(ws + 24 * MB + 512 * KB);   // 128 KB
  float* G_T           = (float*)(ws + 24 * MB + 640 * KB);            // 512 KB
  float* P_T           = (float*)(ws + 25 * MB);                       // 8 MB

  cvt_all<<<560, 256, 0, stream>>>(x, xb, xT, W1, W1t, W2, W2t, W3, W3t0);
  e_gemm<<<dim3(4, 128), 256, 0, stream>>>(xb, W1t, b1, W2t, b2, e1, e2, e1T, e2T);
  atb<<<dim3(16, NSPLIT, 2), 256, 0, stream>>>(e1T, e2T, xT, P_T);
  reduce_g<<<128, 256, 0, stream>>>(P_T, G_T);
  h_mfma<<<dim3(16, 1, 2), 256, 0, stream>>>(G_T, W3, H1t, H2t);
  out_gemm<<<dim3(4, 128), 256, 0, stream>>>(xb, e1, e2, W3t0, H1t, H2t, b3, out);
}